// Round 6
// baseline (307.006 us; speedup 1.0000x reference)
//
#include <hip/hip_runtime.h>
#include <hip/hip_bf16.h>

#define HW 131072      // h*w
#define NCH 128        // channels
#define KS 9
#define L_TOTAL 163840 // Q*M*M
#define NGRP 8         // channel groups == XCDs
#define LPB 256        // l's per block in gather kernel

typedef float        f32x2 __attribute__((ext_vector_type(2)));
typedef float        f32x4 __attribute__((ext_vector_type(4)));
typedef unsigned int u32x2 __attribute__((ext_vector_type(2)));
typedef unsigned int u32x4 __attribute__((ext_vector_type(4)));

static __device__ __forceinline__ float bflo(unsigned int p) { return __uint_as_float(p << 16); }
static __device__ __forceinline__ float bfhi(unsigned int p) { return __uint_as_float(p & 0xffff0000u); }
static __device__ __forceinline__ unsigned short f2bf(float f) {
    unsigned int x = __float_as_uint(f);
    return (unsigned short)((x + 0x7fffu + ((x >> 16) & 1u)) >> 16);  // RNE
}
static __device__ __forceinline__ unsigned int pack2(float a, float b) {
    return (unsigned int)f2bf(a) | ((unsigned int)f2bf(b) << 16);
}

// ---------------------------------------------------------------------------
// Kernel A: transpose x[c][p] (fp32) -> xT slabs: [g][p][8 dwords] where
// slab g holds channels [16g, 16g+16) as bf16 pairs (32 B per row = 4 MB
// per slab = one XCD L2). Also per-p channel mean/max.  (unchanged)
// Grid: HW/128 = 1024 blocks, 256 threads.
// ---------------------------------------------------------------------------
__global__ __launch_bounds__(256) void transpose_x_kernel(
    const f32x2* __restrict__ xf,         // x: [NCH][HW/2] float2 along p
    unsigned int* __restrict__ xT,        // [8][HW][8] dword slabs
    float2* __restrict__ meanmaxP)        // [HW] (mean, max) over channels
{
    __shared__ unsigned short tile[128 * 128];  // [p][col'], rotate swizzle
    __shared__ float ps[4][128];
    __shared__ float pm[4][128];
    const int tid = threadIdx.x;
    const int lane = tid & 63;
    const int wave = tid >> 6;
    const int p0 = blockIdx.x * 128;
    const int pa = 2 * lane, pb = 2 * lane + 1;

    float s0 = 0.f, s1 = 0.f;
    float m0 = -3.4e38f, m1 = -3.4e38f;
    #pragma unroll 8
    for (int it = 0; it < 32; ++it) {
        int c = wave + (it << 2);
        f32x2 v = __builtin_nontemporal_load(&xf[(long)c * (HW / 2) + (p0 >> 1) + lane]);
        tile[pa * 128 + ((c + 2 * pa) & 127)] = f2bf(v.x);
        tile[pb * 128 + ((c + 2 * pb) & 127)] = f2bf(v.y);
        s0 += v.x; s1 += v.y;
        m0 = fmaxf(m0, v.x); m1 = fmaxf(m1, v.y);
    }
    ps[wave][pa] = s0; ps[wave][pb] = s1;
    pm[wave][pa] = m0; pm[wave][pb] = m1;
    __syncthreads();

    #pragma unroll 8
    for (int it = 0; it < 32; ++it) {
        int p = wave + (it << 2);
        int colr = (2 * lane + 2 * p) & 127;          // even -> dword aligned
        unsigned int d = *reinterpret_cast<const unsigned int*>(&tile[p * 128 + colr]);
        // dword holds channels (2*lane, 2*lane+1) -> slab lane>>3, sub lane&7
        xT[((long)(lane >> 3) * HW + (p0 + p)) * 8 + (lane & 7)] = d;
    }
    if (tid < 128) {
        float s = ps[0][tid] + ps[1][tid] + ps[2][tid] + ps[3][tid];
        float m = fmaxf(fmaxf(pm[0][tid], pm[1][tid]), fmaxf(pm[2][tid], pm[3][tid]));
        meanmaxP[p0 + tid] = make_float2(s * 0.0078125f, m);
    }
}

// ---------------------------------------------------------------------------
// Kernel B1: attention multipliers -> PACKED records.
// rec[l][k] = idx (17 bits) | round(sigmoid(logit)*32768) << 17.  (unchanged)
// Grid: L_TOTAL/64 = 2560 blocks, 256 threads.
// ---------------------------------------------------------------------------
__global__ __launch_bounds__(256) void mult_kernel(
    const float2* __restrict__ meanmaxP,       // [HW]
    const int* __restrict__ cks,               // [L][9]
    const float* __restrict__ att_w,           // [9][2][9]
    const float* __restrict__ att_b,           // [9]
    unsigned int* __restrict__ rec)            // [L][12] packed (0..8 used)
{
    __shared__ float attw[162];
    __shared__ float attb[12];
    __shared__ int lcks[64 * 12];
    const int tid = threadIdx.x;
    const int base_l = blockIdx.x * 64;

    if (tid < 162) attw[tid] = att_w[tid];
    if (tid < KS) attb[tid] = att_b[tid];
    for (int j = tid; j < 64 * KS; j += 256) {
        const int lj = j / KS;
        lcks[lj * 12 + (j - lj * KS)] = cks[(long)base_l * KS + j];
    }
    __syncthreads();

    const int l_local = tid >> 2;
    const int sub = tid & 3;
    if (sub < 3) {
        float mean[KS], mx[KS];
        #pragma unroll
        for (int k = 0; k < KS; ++k) {
            float2 mm = meanmaxP[lcks[l_local * 12 + k]];
            mean[k] = mm.x; mx[k] = mm.y;
        }
        #pragma unroll
        for (int oo = 0; oo < 3; ++oo) {
            int o = sub * 3 + oo;
            float logit = attb[o];
            #pragma unroll
            for (int k = 0; k < KS; ++k) {
                logit = fmaf(mean[k], attw[o * 18 + k], logit);
                logit = fmaf(mx[k],   attw[o * 18 + 9 + k], logit);
            }
            float sig = 1.0f / (1.0f + __expf(-logit));
            unsigned int u = (unsigned int)(sig * 32768.0f + 0.5f);
            if (u > 32767u) u = 32767u;
            rec[(long)(base_l + l_local) * 12 + o] =
                (unsigned int)lcks[l_local * 12 + o] | (u << 17);
        }
    }
}

// ---------------------------------------------------------------------------
// Kernel B2: XCD-sliced gather + depthwise. Each thread owns TWO ADJACENT
// l's (2*lq, 2*lq+1) for its 4 channels, so it can pack the (even,odd)
// bf16 pair into one dword and emit ybuf in [c][l-pair] layout -- the
// finalize kernel then needs no transpose at all. Gather request count /
// instruction count per 32 l's identical to round 4.
// Grid: (L_TOTAL/LPB)*8 = 5120 blocks, 256 threads.
// ---------------------------------------------------------------------------
__global__ __launch_bounds__(256, 4) void gather_kernel(
    const unsigned int* __restrict__ xT,       // [8][HW][8]
    const unsigned int* __restrict__ rec,      // [L][12] packed
    const float* __restrict__ depth_w,         // [128][9]
    const float* __restrict__ depth_b,         // [128]
    unsigned int* __restrict__ ybuf,           // [NCH][L/2] bf16 l-pairs
    float* __restrict__ gsum, float* __restrict__ gsq)
{
    __shared__ float dwl[KS][16];   // [k][ch-in-group]
    __shared__ float dbl[16];
    __shared__ float redx[4][4][8]; // [wave][qt][quantity]

    const int tid  = threadIdx.x;
    const int lane = tid & 63;
    const int wave = tid >> 6;
    const int g      = blockIdx.x & 7;
    const int base_l = (blockIdx.x >> 3) * LPB;
    const int qt = lane & 3;        // 8-byte chunk of 32-B row
    const int lq = lane >> 2;       // l-pair selector

    if (tid < 144) {
        int k = tid >> 4, ch = tid & 15;
        dwl[k][ch] = depth_w[(g * 16 + ch) * KS + k];
    }
    if (tid < 16) dbl[tid] = depth_b[g * 16 + tid];
    __syncthreads();

    f32x2 dw[KS][2];
    #pragma unroll
    for (int k = 0; k < KS; ++k) {
        f32x4 t = *(const f32x4*)&dwl[k][qt * 4];
        dw[k][0].x = t.x; dw[k][0].y = t.y;
        dw[k][1].x = t.z; dw[k][1].y = t.w;
    }
    f32x2 db01, db23;
    {
        f32x4 t = *(const f32x4*)&dbl[qt * 4];
        db01.x = t.x; db01.y = t.y; db23.x = t.z; db23.y = t.w;
    }

    const unsigned int* slab = xT + ((size_t)g << 20);            // g*HW*8
    const int LH = L_TOTAL / 2;
    unsigned int* yb = ybuf + (size_t)(g * 16 + qt * 4) * LH + (base_l >> 1);

    f32x2 sum01 = {0.f, 0.f}, sum23 = {0.f, 0.f};
    f32x2 sq01  = {0.f, 0.f}, sq23  = {0.f, 0.f};

    #pragma unroll
    for (int b = 0; b < 2; ++b) {
        const int lw = wave * 64 + b * 32 + 2 * lq;   // local even l
        const unsigned int* rp = rec + (size_t)(base_l + lw) * 12;
        const u32x4 a0 = __builtin_nontemporal_load((const u32x4*)rp);
        const u32x4 a1 = __builtin_nontemporal_load((const u32x4*)(rp + 4));
        const unsigned int a8 = __builtin_nontemporal_load(rp + 8);
        const u32x4 c0 = __builtin_nontemporal_load((const u32x4*)(rp + 12));
        const u32x4 c1 = __builtin_nontemporal_load((const u32x4*)(rp + 16));
        const unsigned int c8 = __builtin_nontemporal_load(rp + 20);
        const unsigned int rA[KS] = {a0.x, a0.y, a0.z, a0.w,
                                     a1.x, a1.y, a1.z, a1.w, a8};
        const unsigned int rB[KS] = {c0.x, c0.y, c0.z, c0.w,
                                     c1.x, c1.y, c1.z, c1.w, c8};

        u32x2 pA[KS], pB[KS];
        #pragma unroll
        for (int k = 0; k < KS; ++k)
            pA[k] = *(const u32x2*)(slab + ((rA[k] & 0x1FFFFu) << 3) + (qt << 1));
        #pragma unroll
        for (int k = 0; k < KS; ++k)
            pB[k] = *(const u32x2*)(slab + ((rB[k] & 0x1FFFFu) << 3) + (qt << 1));

        f32x2 aA01 = db01, aA23 = db23, aB01 = db01, aB23 = db23;
        #pragma unroll
        for (int k = 0; k < KS; ++k) {
            const float mA = fmaf((float)(rA[k] >> 17), 3.0517578125e-5f, 1.0f);
            f32x2 mA2; mA2.x = mA; mA2.y = mA;
            f32x2 xa; xa.x = bflo(pA[k].x); xa.y = bfhi(pA[k].x);
            f32x2 xb; xb.x = bflo(pA[k].y); xb.y = bfhi(pA[k].y);
            aA01 = __builtin_elementwise_fma(xa * mA2, dw[k][0], aA01);
            aA23 = __builtin_elementwise_fma(xb * mA2, dw[k][1], aA23);
            const float mB = fmaf((float)(rB[k] >> 17), 3.0517578125e-5f, 1.0f);
            f32x2 mB2; mB2.x = mB; mB2.y = mB;
            f32x2 ya; ya.x = bflo(pB[k].x); ya.y = bfhi(pB[k].x);
            f32x2 ybv; ybv.x = bflo(pB[k].y); ybv.y = bfhi(pB[k].y);
            aB01 = __builtin_elementwise_fma(ya * mB2, dw[k][0], aB01);
            aB23 = __builtin_elementwise_fma(ybv * mB2, dw[k][1], aB23);
        }

        // [c][l-pair] stores: channel qt*4+j, pair index wave*32 + b*16 + lq
        const int pi = wave * 32 + b * 16 + lq;
        yb[0 * LH + pi] = pack2(aA01.x, aB01.x);
        yb[1 * LH + pi] = pack2(aA01.y, aB01.y);
        yb[2 * LH + pi] = pack2(aA23.x, aB23.x);
        yb[3 * LH + pi] = pack2(aA23.y, aB23.y);

        sum01 += aA01 + aB01; sum23 += aA23 + aB23;
        sq01 = __builtin_elementwise_fma(aA01, aA01, sq01);
        sq01 = __builtin_elementwise_fma(aB01, aB01, sq01);
        sq23 = __builtin_elementwise_fma(aA23, aA23, sq23);
        sq23 = __builtin_elementwise_fma(aB23, aB23, sq23);
    }

    // ---- reduction over lq (lane bits 2..5) via butterfly shuffles ----
    #pragma unroll
    for (int s = 4; s <= 32; s <<= 1) {
        sum01.x += __shfl_xor(sum01.x, s);
        sum01.y += __shfl_xor(sum01.y, s);
        sum23.x += __shfl_xor(sum23.x, s);
        sum23.y += __shfl_xor(sum23.y, s);
        sq01.x  += __shfl_xor(sq01.x,  s);
        sq01.y  += __shfl_xor(sq01.y,  s);
        sq23.x  += __shfl_xor(sq23.x,  s);
        sq23.y  += __shfl_xor(sq23.y,  s);
    }
    if (lane < 4) {
        float* rw = &redx[wave][lane][0];
        rw[0] = sum01.x; rw[1] = sum01.y; rw[2] = sum23.x; rw[3] = sum23.y;
        rw[4] = sq01.x;  rw[5] = sq01.y;  rw[6] = sq23.x;  rw[7] = sq23.y;
    }
    __syncthreads();
    if (tid < 32) {
        const int q = tid >> 2, qq = tid & 3;   // q: quantity, qq: qt
        float s = redx[0][qq][q] + redx[1][qq][q] + redx[2][qq][q] + redx[3][qq][q];
        const int ch = g * 16 + qq * 4 + (q & 3);
        float* dst = (q >= 4) ? gsq : gsum;
        atomicAdd(&dst[ch], s);
    }
}

// ---------------------------------------------------------------------------
// Kernel C: BN finalize + SiLU. ybuf is already [c][l] -- pure coalesced
// stream, no LDS, no transpose. Block = (q, c): reads 32 KB contiguous,
// writes 64 KB contiguous.
// Grid: Q*NCH = 1280 blocks, 256 threads.
// ---------------------------------------------------------------------------
__global__ __launch_bounds__(256) void finalize_kernel(
    const u32x4* __restrict__ ybuf,            // [NCH][L/8] vec4 of l-pairs
    const float* __restrict__ gsum, const float* __restrict__ gsq,
    const float* __restrict__ gamma, const float* __restrict__ beta,
    float* __restrict__ out)                   // [Q*NCH][16384]
{
    const int q = blockIdx.x >> 7;
    const int c = blockIdx.x & 127;
    const int tid = threadIdx.x;

    const float invN = 1.0f / (float)L_TOTAL;
    const float m = gsum[c] * invN;
    const float var = gsq[c] * invN - m * m;
    const float sc = gamma[c] * rsqrtf(var + 1e-5f);
    const float sh = beta[c] - m * sc;

    const u32x4* src = ybuf + (size_t)c * (L_TOTAL / 8) + (size_t)q * 2048;
    float* dst = out + ((size_t)(q * NCH + c) << 14);

    #pragma unroll 2
    for (int it = 0; it < 8; ++it) {
        const int i = it * 256 + tid;
        const u32x4 v = src[i];
        f32x4 o0, o1;
        float z;
        z = fmaf(bflo(v.x), sc, sh); o0.x = z / (1.0f + __expf(-z));
        z = fmaf(bfhi(v.x), sc, sh); o0.y = z / (1.0f + __expf(-z));
        z = fmaf(bflo(v.y), sc, sh); o0.z = z / (1.0f + __expf(-z));
        z = fmaf(bfhi(v.y), sc, sh); o0.w = z / (1.0f + __expf(-z));
        z = fmaf(bflo(v.z), sc, sh); o1.x = z / (1.0f + __expf(-z));
        z = fmaf(bfhi(v.z), sc, sh); o1.y = z / (1.0f + __expf(-z));
        z = fmaf(bflo(v.w), sc, sh); o1.z = z / (1.0f + __expf(-z));
        z = fmaf(bfhi(v.w), sc, sh); o1.w = z / (1.0f + __expf(-z));
        *(f32x4*)&dst[i * 8 + 0] = o0;
        *(f32x4*)&dst[i * 8 + 4] = o1;
    }
}

extern "C" void kernel_launch(void* const* d_in, const int* in_sizes, int n_in,
                              void* d_out, int out_size, void* d_ws, size_t ws_size,
                              hipStream_t stream) {
    const f32x2* x_f2  = (const f32x2*)d_in[0];
    const int* cks     = (const int*)d_in[1];
    const float* aw    = (const float*)d_in[2];
    const float* ab    = (const float*)d_in[3];
    const float* dw    = (const float*)d_in[4];
    const float* db    = (const float*)d_in[5];
    const float* gm    = (const float*)d_in[6];
    const float* bt    = (const float*)d_in[7];

    char* ws = (char*)d_ws;
    unsigned int* xT   = (unsigned int*)ws;                  // 33,554,432 B
    float2* meanmaxP   = (float2*)(ws + 33554432);           // 1,048,576 B
    unsigned int* ybuf = (unsigned int*)(ws + 34603008);     // 41,943,040 B
    unsigned int* rec  = (unsigned int*)(ws + 76546048);     // 7,864,320 B
    float* gsum        = (float*)(ws + 84410368);            // 512 B
    float* gsq         = gsum + NCH;                         // 512 B

    hipMemsetAsync(gsum, 0, 2 * NCH * sizeof(float), stream);

    transpose_x_kernel<<<HW / 128, 256, 0, stream>>>(x_f2, xT, meanmaxP);
    mult_kernel<<<L_TOTAL / 64, 256, 0, stream>>>(meanmaxP, cks, aw, ab, rec);
    gather_kernel<<<(L_TOTAL / LPB) * NGRP, 256, 0, stream>>>(
        xT, rec, dw, db, ybuf, gsum, gsq);
    finalize_kernel<<<1280, 256, 0, stream>>>(
        (const u32x4*)ybuf, gsum, gsq, gm, bt, (float*)d_out);
}

// Round 7
// 280.732 us; speedup vs baseline: 1.0936x; 1.0936x over previous
//
#include <hip/hip_runtime.h>
#include <hip/hip_bf16.h>

#define HW 131072      // h*w
#define NCH 128        // channels
#define KS 9
#define L_TOTAL 163840 // Q*M*M
#define NGRP 8         // channel groups == XCDs
#define LPB 256        // l's per block in gather kernel

typedef float        f32x2 __attribute__((ext_vector_type(2)));
typedef float        f32x4 __attribute__((ext_vector_type(4)));
typedef unsigned int u32x2 __attribute__((ext_vector_type(2)));
typedef unsigned int u32x4 __attribute__((ext_vector_type(4)));

static __device__ __forceinline__ float bflo(unsigned int p) { return __uint_as_float(p << 16); }
static __device__ __forceinline__ float bfhi(unsigned int p) { return __uint_as_float(p & 0xffff0000u); }
static __device__ __forceinline__ unsigned short f2bf(float f) {
    unsigned int x = __float_as_uint(f);
    return (unsigned short)((x + 0x7fffu + ((x >> 16) & 1u)) >> 16);  // RNE
}

// ---------------------------------------------------------------------------
// Kernel A: transpose x[c][p] (fp32) -> xT slabs: [g][p][8 dwords]; slab g
// holds channels [16g,16g+16) as bf16 pairs (32 B row = 4 MB = one XCD L2).
// NEW: store loop remapped so each wave writes 256-B contiguous runs per
// slab (was 8x 32-B fragments at 4-MB strides -> RMW fetch + L2 pollution).
// Grid: HW/128 = 1024 blocks, 256 threads.
// ---------------------------------------------------------------------------
__global__ __launch_bounds__(256) void transpose_x_kernel(
    const f32x2* __restrict__ xf,         // x: [NCH][HW/2] float2 along p
    unsigned int* __restrict__ xT,        // [8][HW][8] dword slabs
    float2* __restrict__ meanmaxP)        // [HW] (mean, max) over channels
{
    __shared__ unsigned short tile[128 * 128];  // [p][col'], rotate swizzle
    __shared__ float ps[4][128];
    __shared__ float pm[4][128];
    const int tid = threadIdx.x;
    const int lane = tid & 63;
    const int wave = tid >> 6;
    const int p0 = blockIdx.x * 128;
    const int pa = 2 * lane, pb = 2 * lane + 1;

    float s0 = 0.f, s1 = 0.f;
    float m0 = -3.4e38f, m1 = -3.4e38f;
    #pragma unroll 8
    for (int it = 0; it < 32; ++it) {
        int c = wave + (it << 2);
        f32x2 v = __builtin_nontemporal_load(&xf[(long)c * (HW / 2) + (p0 >> 1) + lane]);
        tile[pa * 128 + ((c + 2 * pa) & 127)] = f2bf(v.x);
        tile[pb * 128 + ((c + 2 * pb) & 127)] = f2bf(v.y);
        s0 += v.x; s1 += v.y;
        m0 = fmaxf(m0, v.x); m1 = fmaxf(m1, v.y);
    }
    ps[wave][pa] = s0; ps[wave][pb] = s1;
    pm[wave][pa] = m0; pm[wave][pb] = m1;
    __syncthreads();

    // store: idx -> (slab s, p, dword d); 64 consecutive idx = same slab,
    // 8 p x 8 d = 256 B contiguous per wave store burst.
    #pragma unroll 8
    for (int it = 0; it < 32; ++it) {
        int idx = it * 256 + tid;              // [0, 8192)
        int s = idx >> 10;                     // slab (1024 dwords each)
        int rem = idx & 1023;
        int p = rem >> 3;
        int d = rem & 7;
        int cpair = s * 8 + d;                 // dword holds ch (2cpair, 2cpair+1)
        unsigned int u = *reinterpret_cast<const unsigned int*>(
            &tile[p * 128 + ((2 * cpair + 2 * p) & 127)]);
        xT[((long)s * HW + (p0 + p)) * 8 + d] = u;
    }
    if (tid < 128) {
        float s = ps[0][tid] + ps[1][tid] + ps[2][tid] + ps[3][tid];
        float m = fmaxf(fmaxf(pm[0][tid], pm[1][tid]), fmaxf(pm[2][tid], pm[3][tid]));
        meanmaxP[p0 + tid] = make_float2(s * 0.0078125f, m);
    }
}

// ---------------------------------------------------------------------------
// Kernel B1: attention multipliers -> PACKED records.
// rec[l][k] = idx (17 bits) | round(sigmoid(logit)*32768) << 17.
// NEW: block 0 also zeroes gsum/gsq (replaces the hipMemsetAsync dispatch;
// mult runs before gather in stream order).
// Grid: L_TOTAL/64 = 2560 blocks, 256 threads.
// ---------------------------------------------------------------------------
__global__ __launch_bounds__(256) void mult_kernel(
    const float2* __restrict__ meanmaxP,       // [HW]
    const int* __restrict__ cks,               // [L][9]
    const float* __restrict__ att_w,           // [9][2][9]
    const float* __restrict__ att_b,           // [9]
    unsigned int* __restrict__ rec,            // [L][12] packed (0..8 used)
    float* __restrict__ gz)                    // gsum(128)+gsq(128) contiguous
{
    __shared__ float attw[162];
    __shared__ float attb[12];
    __shared__ int lcks[64 * 12];
    const int tid = threadIdx.x;
    const int base_l = blockIdx.x * 64;

    if (blockIdx.x == 0) gz[tid] = 0.f;        // 256 floats = gsum + gsq

    if (tid < 162) attw[tid] = att_w[tid];
    if (tid < KS) attb[tid] = att_b[tid];
    for (int j = tid; j < 64 * KS; j += 256) {
        const int lj = j / KS;
        lcks[lj * 12 + (j - lj * KS)] = cks[(long)base_l * KS + j];
    }
    __syncthreads();

    const int l_local = tid >> 2;
    const int sub = tid & 3;
    if (sub < 3) {
        float mean[KS], mx[KS];
        #pragma unroll
        for (int k = 0; k < KS; ++k) {
            float2 mm = meanmaxP[lcks[l_local * 12 + k]];
            mean[k] = mm.x; mx[k] = mm.y;
        }
        #pragma unroll
        for (int oo = 0; oo < 3; ++oo) {
            int o = sub * 3 + oo;
            float logit = attb[o];
            #pragma unroll
            for (int k = 0; k < KS; ++k) {
                logit = fmaf(mean[k], attw[o * 18 + k], logit);
                logit = fmaf(mx[k],   attw[o * 18 + 9 + k], logit);
            }
            float sig = 1.0f / (1.0f + __expf(-logit));
            unsigned int u = (unsigned int)(sig * 32768.0f + 0.5f);
            if (u > 32767u) u = 32767u;
            rec[(long)(base_l + l_local) * 12 + o] =
                (unsigned int)lcks[l_local * 12 + o] | (u << 17);
        }
    }
}

// ---------------------------------------------------------------------------
// Kernel B2: XCD-sliced gather + depthwise. Round-4 proven core (1 l per
// thread, qt = lane&3 owns 4 channels, 9x u32x2 gathers, VGPR ~40).
// NEW: results staged in LDS ushort[16][264] tile, flushed at block end as
// 16 channels x 512 B contiguous -> full-line stores in [c][l] layout
// (round 6's direct scattered 64-B stores caused +35 MB RMW fetch).
// Grid: (L_TOTAL/LPB)*8 = 5120 blocks, 256 threads.
// ---------------------------------------------------------------------------
__global__ __launch_bounds__(256, 4) void gather_kernel(
    const unsigned int* __restrict__ xT,       // [8][HW][8]
    const unsigned int* __restrict__ rec,      // [L][12] packed
    const float* __restrict__ depth_w,         // [128][9]
    const float* __restrict__ depth_b,         // [128]
    unsigned int* __restrict__ ybuf,           // [NCH][L/2] bf16 l-pairs
    float* __restrict__ gsum, float* __restrict__ gsq)
{
    __shared__ float dwl[KS][16];   // [k][ch-in-group]
    __shared__ float dbl[16];
    __shared__ float redx[4][4][8]; // [wave][qt][quantity]
    __shared__ __align__(16) unsigned short ytile[16][264]; // [ch][l], pad 264

    const int tid  = threadIdx.x;
    const int lane = tid & 63;
    const int wave = tid >> 6;
    const int g      = blockIdx.x & 7;
    const int base_l = (blockIdx.x >> 3) * LPB;
    const int qt = lane & 3;        // 8-byte chunk of 32-B row
    const int lq = lane >> 2;       // l within batch of 16

    if (tid < 144) {
        int k = tid >> 4, ch = tid & 15;
        dwl[k][ch] = depth_w[(g * 16 + ch) * KS + k];
    }
    if (tid < 16) dbl[tid] = depth_b[g * 16 + tid];
    __syncthreads();

    f32x2 dw[KS][2];
    #pragma unroll
    for (int k = 0; k < KS; ++k) {
        f32x4 t = *(const f32x4*)&dwl[k][qt * 4];
        dw[k][0].x = t.x; dw[k][0].y = t.y;
        dw[k][1].x = t.z; dw[k][1].y = t.w;
    }
    f32x2 db01, db23;
    {
        f32x4 t = *(const f32x4*)&dbl[qt * 4];
        db01.x = t.x; db01.y = t.y; db23.x = t.z; db23.y = t.w;
    }

    const unsigned int* slab = xT + ((size_t)g << 20);            // g*HW*8

    f32x2 sum01 = {0.f, 0.f}, sum23 = {0.f, 0.f};
    f32x2 sq01  = {0.f, 0.f}, sq23  = {0.f, 0.f};

    #pragma unroll
    for (int b = 0; b < 4; ++b) {
        const int lloc = wave * 64 + b * 16 + lq;  // local l in [0,256)
        const unsigned int* rp = rec + (size_t)(base_l + lloc) * 12;
        const u32x4 r0 = __builtin_nontemporal_load((const u32x4*)rp);
        const u32x4 r1 = __builtin_nontemporal_load((const u32x4*)(rp + 4));
        const unsigned int r8 = __builtin_nontemporal_load(rp + 8);
        const unsigned int rr[KS] = {r0.x, r0.y, r0.z, r0.w,
                                     r1.x, r1.y, r1.z, r1.w, r8};

        u32x2 pv[KS];
        #pragma unroll
        for (int k = 0; k < KS; ++k)
            pv[k] = *(const u32x2*)(slab + ((rr[k] & 0x1FFFFu) << 3) + (qt << 1));

        f32x2 acc01 = db01, acc23 = db23;
        #pragma unroll
        for (int k = 0; k < KS; ++k) {
            const float mk = fmaf((float)(rr[k] >> 17), 3.0517578125e-5f, 1.0f);
            f32x2 mk2; mk2.x = mk; mk2.y = mk;
            f32x2 xa; xa.x = bflo(pv[k].x); xa.y = bfhi(pv[k].x);
            f32x2 xb; xb.x = bflo(pv[k].y); xb.y = bfhi(pv[k].y);
            acc01 = __builtin_elementwise_fma(xa * mk2, dw[k][0], acc01);
            acc23 = __builtin_elementwise_fma(xb * mk2, dw[k][1], acc23);
        }

        // stage 4 channel values for this l into the LDS tile
        ytile[qt * 4 + 0][lloc] = f2bf(acc01.x);
        ytile[qt * 4 + 1][lloc] = f2bf(acc01.y);
        ytile[qt * 4 + 2][lloc] = f2bf(acc23.x);
        ytile[qt * 4 + 3][lloc] = f2bf(acc23.y);

        sum01 += acc01; sum23 += acc23;
        sq01 = __builtin_elementwise_fma(acc01, acc01, sq01);
        sq23 = __builtin_elementwise_fma(acc23, acc23, sq23);
    }

    __syncthreads();   // ytile complete

    // ---- flush: 16 channels x 512 B contiguous (full-line stores) ----
    {
        const int ch = tid >> 4;
        const int m  = tid & 15;               // 8-dword chunk within row
        const u32x4 v0 = *(const u32x4*)&ytile[ch][m * 16];
        const u32x4 v1 = *(const u32x4*)&ytile[ch][m * 16 + 8];
        unsigned int* dst = ybuf + (size_t)(g * 16 + ch) * (L_TOTAL / 2)
                          + (base_l >> 1) + m * 8;
        *(u32x4*)dst = v0;
        *(u32x4*)(dst + 4) = v1;
    }

    // ---- reduction over lq (lane bits 2..5) via butterfly shuffles ----
    #pragma unroll
    for (int s = 4; s <= 32; s <<= 1) {
        sum01.x += __shfl_xor(sum01.x, s);
        sum01.y += __shfl_xor(sum01.y, s);
        sum23.x += __shfl_xor(sum23.x, s);
        sum23.y += __shfl_xor(sum23.y, s);
        sq01.x  += __shfl_xor(sq01.x,  s);
        sq01.y  += __shfl_xor(sq01.y,  s);
        sq23.x  += __shfl_xor(sq23.x,  s);
        sq23.y  += __shfl_xor(sq23.y,  s);
    }
    if (lane < 4) {
        float* rw = &redx[wave][lane][0];
        rw[0] = sum01.x; rw[1] = sum01.y; rw[2] = sum23.x; rw[3] = sum23.y;
        rw[4] = sq01.x;  rw[5] = sq01.y;  rw[6] = sq23.x;  rw[7] = sq23.y;
    }
    __syncthreads();
    if (tid < 32) {
        const int q = tid >> 2, qq = tid & 3;   // q: quantity, qq: qt
        float s = redx[0][qq][q] + redx[1][qq][q] + redx[2][qq][q] + redx[3][qq][q];
        const int ch = g * 16 + qq * 4 + (q & 3);
        float* dst = (q >= 4) ? gsq : gsum;
        atomicAdd(&dst[ch], s);
    }
}

// ---------------------------------------------------------------------------
// Kernel C: BN finalize + SiLU. ybuf is [c][l] -- pure coalesced stream,
// no LDS, no transpose. Block = (q, c): reads 32 KB contiguous, writes
// 64 KB contiguous.  (unchanged)
// Grid: Q*NCH = 1280 blocks, 256 threads.
// ---------------------------------------------------------------------------
__global__ __launch_bounds__(256) void finalize_kernel(
    const u32x4* __restrict__ ybuf,            // [NCH][L/8] vec4 of l-pairs
    const float* __restrict__ gsum, const float* __restrict__ gsq,
    const float* __restrict__ gamma, const float* __restrict__ beta,
    float* __restrict__ out)                   // [Q*NCH][16384]
{
    const int q = blockIdx.x >> 7;
    const int c = blockIdx.x & 127;
    const int tid = threadIdx.x;

    const float invN = 1.0f / (float)L_TOTAL;
    const float m = gsum[c] * invN;
    const float var = gsq[c] * invN - m * m;
    const float sc = gamma[c] * rsqrtf(var + 1e-5f);
    const float sh = beta[c] - m * sc;

    const u32x4* src = ybuf + (size_t)c * (L_TOTAL / 8) + (size_t)q * 2048;
    float* dst = out + ((size_t)(q * NCH + c) << 14);

    #pragma unroll 2
    for (int it = 0; it < 8; ++it) {
        const int i = it * 256 + tid;
        const u32x4 v = src[i];
        f32x4 o0, o1;
        float z;
        z = fmaf(bflo(v.x), sc, sh); o0.x = z / (1.0f + __expf(-z));
        z = fmaf(bfhi(v.x), sc, sh); o0.y = z / (1.0f + __expf(-z));
        z = fmaf(bflo(v.y), sc, sh); o0.z = z / (1.0f + __expf(-z));
        z = fmaf(bfhi(v.y), sc, sh); o0.w = z / (1.0f + __expf(-z));
        z = fmaf(bflo(v.z), sc, sh); o1.x = z / (1.0f + __expf(-z));
        z = fmaf(bfhi(v.z), sc, sh); o1.y = z / (1.0f + __expf(-z));
        z = fmaf(bflo(v.w), sc, sh); o1.z = z / (1.0f + __expf(-z));
        z = fmaf(bfhi(v.w), sc, sh); o1.w = z / (1.0f + __expf(-z));
        *(f32x4*)&dst[i * 8 + 0] = o0;
        *(f32x4*)&dst[i * 8 + 4] = o1;
    }
}

extern "C" void kernel_launch(void* const* d_in, const int* in_sizes, int n_in,
                              void* d_out, int out_size, void* d_ws, size_t ws_size,
                              hipStream_t stream) {
    const f32x2* x_f2  = (const f32x2*)d_in[0];
    const int* cks     = (const int*)d_in[1];
    const float* aw    = (const float*)d_in[2];
    const float* ab    = (const float*)d_in[3];
    const float* dw    = (const float*)d_in[4];
    const float* db    = (const float*)d_in[5];
    const float* gm    = (const float*)d_in[6];
    const float* bt    = (const float*)d_in[7];

    char* ws = (char*)d_ws;
    unsigned int* xT   = (unsigned int*)ws;                  // 33,554,432 B
    float2* meanmaxP   = (float2*)(ws + 33554432);           // 1,048,576 B
    unsigned int* ybuf = (unsigned int*)(ws + 34603008);     // 41,943,040 B
    unsigned int* rec  = (unsigned int*)(ws + 76546048);     // 7,864,320 B
    float* gsum        = (float*)(ws + 84410368);            // 512 B
    float* gsq         = gsum + NCH;                         // 512 B

    transpose_x_kernel<<<HW / 128, 256, 0, stream>>>(x_f2, xT, meanmaxP);
    mult_kernel<<<L_TOTAL / 64, 256, 0, stream>>>(meanmaxP, cks, aw, ab, rec, gsum);
    gather_kernel<<<(L_TOTAL / LPB) * NGRP, 256, 0, stream>>>(
        xT, rec, dw, db, ybuf, gsum, gsq);
    finalize_kernel<<<1280, 256, 0, stream>>>(
        (const u32x4*)ybuf, gsum, gsq, gm, bt, (float*)d_out);
}

// Round 8
// 280.557 us; speedup vs baseline: 1.0943x; 1.0006x over previous
//
#include <hip/hip_runtime.h>
#include <hip/hip_bf16.h>

#define HW 131072      // h*w
#define NCH 128        // channels
#define KS 9
#define L_TOTAL 163840 // Q*M*M
#define NGRP 8         // channel groups == XCDs
#define LPB 256        // l's per block in gather kernel

typedef float        f32x2 __attribute__((ext_vector_type(2)));
typedef float        f32x4 __attribute__((ext_vector_type(4)));
typedef unsigned int u32x2 __attribute__((ext_vector_type(2)));
typedef unsigned int u32x4 __attribute__((ext_vector_type(4)));

static __device__ __forceinline__ float bflo(unsigned int p) { return __uint_as_float(p << 16); }
static __device__ __forceinline__ float bfhi(unsigned int p) { return __uint_as_float(p & 0xffff0000u); }
static __device__ __forceinline__ unsigned short f2bf(float f) {
    unsigned int x = __float_as_uint(f);
    return (unsigned short)((x + 0x7fffu + ((x >> 16) & 1u)) >> 16);  // RNE
}

// ---------------------------------------------------------------------------
// Kernel A: transpose x[c][p] (fp32) -> xT slabs [g][p][8 dwords]; slab g
// holds channels [16g,16g+16) as bf16 pairs (32-B row = 4 MB = one XCD L2).
// NEW: f32x4 loads (16 B/lane, half the load instrs) and u32x2 stores
// (512 B contiguous per wave burst). meanmax partials: lane owns 4 p's,
// 8 c-groups reduced via LDS.
// Grid: HW/128 = 1024 blocks, 256 threads.
// ---------------------------------------------------------------------------
__global__ __launch_bounds__(256) void transpose_x_kernel(
    const f32x4* __restrict__ xf4,        // x: [NCH][HW/4] float4 along p
    unsigned int* __restrict__ xT,        // [8][HW][8] dword slabs
    float2* __restrict__ meanmaxP)        // [HW] (mean, max) over channels
{
    __shared__ unsigned short tile[128 * 128];  // [p][col'], rotate swizzle
    __shared__ float ps[8][128];
    __shared__ float pm[8][128];
    const int tid = threadIdx.x;
    const int p0 = blockIdx.x * 128;
    const int pj = tid & 31;          // f32x4 slot -> p's 4pj..4pj+3
    const int cg = tid >> 5;          // c-group (8 groups)

    float s0 = 0.f, s1 = 0.f, s2 = 0.f, s3 = 0.f;
    float m0 = -3.4e38f, m1 = -3.4e38f, m2 = -3.4e38f, m3 = -3.4e38f;
    #pragma unroll 4
    for (int it = 0; it < 16; ++it) {
        const int c = cg + (it << 3);
        const f32x4 v = __builtin_nontemporal_load(&xf4[(long)c * (HW / 4) + (p0 >> 2) + pj]);
        const int pA = 4 * pj;
        tile[(pA + 0) * 128 + ((c + 2 * (pA + 0)) & 127)] = f2bf(v.x);
        tile[(pA + 1) * 128 + ((c + 2 * (pA + 1)) & 127)] = f2bf(v.y);
        tile[(pA + 2) * 128 + ((c + 2 * (pA + 2)) & 127)] = f2bf(v.z);
        tile[(pA + 3) * 128 + ((c + 2 * (pA + 3)) & 127)] = f2bf(v.w);
        s0 += v.x; s1 += v.y; s2 += v.z; s3 += v.w;
        m0 = fmaxf(m0, v.x); m1 = fmaxf(m1, v.y);
        m2 = fmaxf(m2, v.z); m3 = fmaxf(m3, v.w);
    }
    {
        const int pA = 4 * pj;
        ps[cg][pA + 0] = s0; ps[cg][pA + 1] = s1;
        ps[cg][pA + 2] = s2; ps[cg][pA + 3] = s3;
        pm[cg][pA + 0] = m0; pm[cg][pA + 1] = m1;
        pm[cg][pA + 2] = m2; pm[cg][pA + 3] = m3;
    }
    __syncthreads();

    // store: idx2 -> (slab s, p, dword-pair dp); wave = 512 B contiguous.
    #pragma unroll 4
    for (int it = 0; it < 16; ++it) {
        const int idx2 = it * 256 + tid;       // [0, 4096) u32x2 units
        const int s = idx2 >> 9;               // slab (512 u32x2 each)
        const int rem = idx2 & 511;
        const int p = rem >> 2;
        const int dp = rem & 3;                // dword pair within 32-B row
        const int cpair = s * 8 + 2 * dp;      // dword d=2dp holds ch pair cpair
        const int col0 = (2 * cpair + 2 * p) & 127;
        const int col1 = (2 * cpair + 2 + 2 * p) & 127;
        u32x2 u;
        u.x = *reinterpret_cast<const unsigned int*>(&tile[p * 128 + col0]);
        u.y = *reinterpret_cast<const unsigned int*>(&tile[p * 128 + col1]);
        *(u32x2*)&xT[((long)s * HW + (p0 + p)) * 8 + 2 * dp] = u;
    }
    if (tid < 128) {
        float s = 0.f, m = -3.4e38f;
        #pragma unroll
        for (int g2 = 0; g2 < 8; ++g2) {
            s += ps[g2][tid];
            m = fmaxf(m, pm[g2][tid]);
        }
        meanmaxP[p0 + tid] = make_float2(s * 0.0078125f, m);
    }
}

// ---------------------------------------------------------------------------
// Kernel B1: attention multipliers -> PACKED records.
// rec[l][k] = idx (17 bits) | round(sigmoid(logit)*32768) << 17.
// NEW: thread-per-l (was 3 threads per l each loading the SAME 9 meanmax
// values -> 3x redundant random loads + 25% idle lanes). rec rows built
// in LDS, flushed as fully-coalesced u32x4 stores. Block 0 zeroes gsum/gsq.
// Grid: L_TOTAL/256 = 640 blocks, 256 threads.
// ---------------------------------------------------------------------------
__global__ __launch_bounds__(256) void mult_kernel(
    const float2* __restrict__ meanmaxP,       // [HW]
    const int* __restrict__ cks,               // [L][9]
    const float* __restrict__ att_w,           // [9][2][9]
    const float* __restrict__ att_b,           // [9]
    unsigned int* __restrict__ rec,            // [L][12] packed (0..8 used)
    float* __restrict__ gz)                    // gsum(128)+gsq(128) contiguous
{
    __shared__ float attw[162];
    __shared__ float attb[12];
    __shared__ __align__(16) unsigned int lrec[256 * 12];   // 12 KB
    const int tid = threadIdx.x;
    const int base_l = blockIdx.x * 256;

    if (blockIdx.x == 0) gz[tid] = 0.f;        // 256 floats = gsum + gsq

    if (tid < 162) attw[tid] = att_w[tid];
    if (tid < KS) attb[tid] = att_b[tid];
    for (int j = tid; j < 256 * KS; j += 256) {
        const int lj = j / KS;
        lrec[lj * 12 + (j - lj * KS)] = (unsigned int)cks[(long)base_l * KS + j];
    }
    __syncthreads();

    unsigned int idx[KS];
    float mean[KS], mx[KS];
    #pragma unroll
    for (int k = 0; k < KS; ++k) {
        idx[k] = lrec[tid * 12 + k];
        const float2 mm = meanmaxP[idx[k]];
        mean[k] = mm.x; mx[k] = mm.y;
    }
    #pragma unroll
    for (int o = 0; o < KS; ++o) {
        float logit = attb[o];
        #pragma unroll
        for (int k = 0; k < KS; ++k) {
            logit = fmaf(mean[k], attw[o * 18 + k], logit);
            logit = fmaf(mx[k],   attw[o * 18 + 9 + k], logit);
        }
        const float sig = 1.0f / (1.0f + __expf(-logit));
        unsigned int u = (unsigned int)(sig * 32768.0f + 0.5f);
        if (u > 32767u) u = 32767u;
        lrec[tid * 12 + o] = idx[o] | (u << 17);
    }
    __syncthreads();

    // coalesced flush: 3072 dwords = 768 u32x4 (pad slots carry garbage,
    // never read downstream)
    const u32x4* lv = (const u32x4*)lrec;
    u32x4* dst = (u32x4*)(rec + (size_t)base_l * 12);
    #pragma unroll
    for (int j = 0; j < 3; ++j)
        dst[j * 256 + tid] = lv[j * 256 + tid];
}

// ---------------------------------------------------------------------------
// Kernel B2: XCD-sliced gather + depthwise.  (unchanged — proven 105.9 µs;
// at the ~5.9 random-row-requests/cyc/XCD L2 wall across 3 structures)
// Grid: (L_TOTAL/LPB)*8 = 5120 blocks, 256 threads.
// ---------------------------------------------------------------------------
__global__ __launch_bounds__(256, 4) void gather_kernel(
    const unsigned int* __restrict__ xT,       // [8][HW][8]
    const unsigned int* __restrict__ rec,      // [L][12] packed
    const float* __restrict__ depth_w,         // [128][9]
    const float* __restrict__ depth_b,         // [128]
    unsigned int* __restrict__ ybuf,           // [NCH][L/2] bf16 l-pairs
    float* __restrict__ gsum, float* __restrict__ gsq)
{
    __shared__ float dwl[KS][16];   // [k][ch-in-group]
    __shared__ float dbl[16];
    __shared__ float redx[4][4][8]; // [wave][qt][quantity]
    __shared__ __align__(16) unsigned short ytile[16][264]; // [ch][l], pad 264

    const int tid  = threadIdx.x;
    const int lane = tid & 63;
    const int wave = tid >> 6;
    const int g      = blockIdx.x & 7;
    const int base_l = (blockIdx.x >> 3) * LPB;
    const int qt = lane & 3;        // 8-byte chunk of 32-B row
    const int lq = lane >> 2;       // l within batch of 16

    if (tid < 144) {
        int k = tid >> 4, ch = tid & 15;
        dwl[k][ch] = depth_w[(g * 16 + ch) * KS + k];
    }
    if (tid < 16) dbl[tid] = depth_b[g * 16 + tid];
    __syncthreads();

    f32x2 dw[KS][2];
    #pragma unroll
    for (int k = 0; k < KS; ++k) {
        f32x4 t = *(const f32x4*)&dwl[k][qt * 4];
        dw[k][0].x = t.x; dw[k][0].y = t.y;
        dw[k][1].x = t.z; dw[k][1].y = t.w;
    }
    f32x2 db01, db23;
    {
        f32x4 t = *(const f32x4*)&dbl[qt * 4];
        db01.x = t.x; db01.y = t.y; db23.x = t.z; db23.y = t.w;
    }

    const unsigned int* slab = xT + ((size_t)g << 20);            // g*HW*8

    f32x2 sum01 = {0.f, 0.f}, sum23 = {0.f, 0.f};
    f32x2 sq01  = {0.f, 0.f}, sq23  = {0.f, 0.f};

    #pragma unroll
    for (int b = 0; b < 4; ++b) {
        const int lloc = wave * 64 + b * 16 + lq;  // local l in [0,256)
        const unsigned int* rp = rec + (size_t)(base_l + lloc) * 12;
        const u32x4 r0 = __builtin_nontemporal_load((const u32x4*)rp);
        const u32x4 r1 = __builtin_nontemporal_load((const u32x4*)(rp + 4));
        const unsigned int r8 = __builtin_nontemporal_load(rp + 8);
        const unsigned int rr[KS] = {r0.x, r0.y, r0.z, r0.w,
                                     r1.x, r1.y, r1.z, r1.w, r8};

        u32x2 pv[KS];
        #pragma unroll
        for (int k = 0; k < KS; ++k)
            pv[k] = *(const u32x2*)(slab + ((rr[k] & 0x1FFFFu) << 3) + (qt << 1));

        f32x2 acc01 = db01, acc23 = db23;
        #pragma unroll
        for (int k = 0; k < KS; ++k) {
            const float mk = fmaf((float)(rr[k] >> 17), 3.0517578125e-5f, 1.0f);
            f32x2 mk2; mk2.x = mk; mk2.y = mk;
            f32x2 xa; xa.x = bflo(pv[k].x); xa.y = bfhi(pv[k].x);
            f32x2 xb; xb.x = bflo(pv[k].y); xb.y = bfhi(pv[k].y);
            acc01 = __builtin_elementwise_fma(xa * mk2, dw[k][0], acc01);
            acc23 = __builtin_elementwise_fma(xb * mk2, dw[k][1], acc23);
        }

        // stage 4 channel values for this l into the LDS tile
        ytile[qt * 4 + 0][lloc] = f2bf(acc01.x);
        ytile[qt * 4 + 1][lloc] = f2bf(acc01.y);
        ytile[qt * 4 + 2][lloc] = f2bf(acc23.x);
        ytile[qt * 4 + 3][lloc] = f2bf(acc23.y);

        sum01 += acc01; sum23 += acc23;
        sq01 = __builtin_elementwise_fma(acc01, acc01, sq01);
        sq23 = __builtin_elementwise_fma(acc23, acc23, sq23);
    }

    __syncthreads();   // ytile complete

    // ---- flush: 16 channels x 512 B contiguous (full-line stores) ----
    {
        const int ch = tid >> 4;
        const int m  = tid & 15;               // 8-dword chunk within row
        const u32x4 v0 = *(const u32x4*)&ytile[ch][m * 16];
        const u32x4 v1 = *(const u32x4*)&ytile[ch][m * 16 + 8];
        unsigned int* dst = ybuf + (size_t)(g * 16 + ch) * (L_TOTAL / 2)
                          + (base_l >> 1) + m * 8;
        *(u32x4*)dst = v0;
        *(u32x4*)(dst + 4) = v1;
    }

    // ---- reduction over lq (lane bits 2..5) via butterfly shuffles ----
    #pragma unroll
    for (int s = 4; s <= 32; s <<= 1) {
        sum01.x += __shfl_xor(sum01.x, s);
        sum01.y += __shfl_xor(sum01.y, s);
        sum23.x += __shfl_xor(sum23.x, s);
        sum23.y += __shfl_xor(sum23.y, s);
        sq01.x  += __shfl_xor(sq01.x,  s);
        sq01.y  += __shfl_xor(sq01.y,  s);
        sq23.x  += __shfl_xor(sq23.x,  s);
        sq23.y  += __shfl_xor(sq23.y,  s);
    }
    if (lane < 4) {
        float* rw = &redx[wave][lane][0];
        rw[0] = sum01.x; rw[1] = sum01.y; rw[2] = sum23.x; rw[3] = sum23.y;
        rw[4] = sq01.x;  rw[5] = sq01.y;  rw[6] = sq23.x;  rw[7] = sq23.y;
    }
    __syncthreads();
    if (tid < 32) {
        const int q = tid >> 2, qq = tid & 3;   // q: quantity, qq: qt
        float s = redx[0][qq][q] + redx[1][qq][q] + redx[2][qq][q] + redx[3][qq][q];
        const int ch = g * 16 + qq * 4 + (q & 3);
        float* dst = (q >= 4) ? gsq : gsum;
        atomicAdd(&dst[ch], s);
    }
}

// ---------------------------------------------------------------------------
// Kernel C: BN finalize + SiLU. ybuf is [c][l] -- pure coalesced stream.
// Block = (q, c): reads 32 KB contiguous, writes 64 KB contiguous.
// Grid: Q*NCH = 1280 blocks, 256 threads.  (unchanged)
// ---------------------------------------------------------------------------
__global__ __launch_bounds__(256) void finalize_kernel(
    const u32x4* __restrict__ ybuf,            // [NCH][L/8] vec4 of l-pairs
    const float* __restrict__ gsum, const float* __restrict__ gsq,
    const float* __restrict__ gamma, const float* __restrict__ beta,
    float* __restrict__ out)                   // [Q*NCH][16384]
{
    const int q = blockIdx.x >> 7;
    const int c = blockIdx.x & 127;
    const int tid = threadIdx.x;

    const float invN = 1.0f / (float)L_TOTAL;
    const float m = gsum[c] * invN;
    const float var = gsq[c] * invN - m * m;
    const float sc = gamma[c] * rsqrtf(var + 1e-5f);
    const float sh = beta[c] - m * sc;

    const u32x4* src = ybuf + (size_t)c * (L_TOTAL / 8) + (size_t)q * 2048;
    float* dst = out + ((size_t)(q * NCH + c) << 14);

    #pragma unroll 2
    for (int it = 0; it < 8; ++it) {
        const int i = it * 256 + tid;
        const u32x4 v = src[i];
        f32x4 o0, o1;
        float z;
        z = fmaf(bflo(v.x), sc, sh); o0.x = z / (1.0f + __expf(-z));
        z = fmaf(bfhi(v.x), sc, sh); o0.y = z / (1.0f + __expf(-z));
        z = fmaf(bflo(v.y), sc, sh); o0.z = z / (1.0f + __expf(-z));
        z = fmaf(bfhi(v.y), sc, sh); o0.w = z / (1.0f + __expf(-z));
        z = fmaf(bflo(v.z), sc, sh); o1.x = z / (1.0f + __expf(-z));
        z = fmaf(bfhi(v.z), sc, sh); o1.y = z / (1.0f + __expf(-z));
        z = fmaf(bflo(v.w), sc, sh); o1.z = z / (1.0f + __expf(-z));
        z = fmaf(bfhi(v.w), sc, sh); o1.w = z / (1.0f + __expf(-z));
        *(f32x4*)&dst[i * 8 + 0] = o0;
        *(f32x4*)&dst[i * 8 + 4] = o1;
    }
}

extern "C" void kernel_launch(void* const* d_in, const int* in_sizes, int n_in,
                              void* d_out, int out_size, void* d_ws, size_t ws_size,
                              hipStream_t stream) {
    const f32x4* x_f4  = (const f32x4*)d_in[0];
    const int* cks     = (const int*)d_in[1];
    const float* aw    = (const float*)d_in[2];
    const float* ab    = (const float*)d_in[3];
    const float* dw    = (const float*)d_in[4];
    const float* db    = (const float*)d_in[5];
    const float* gm    = (const float*)d_in[6];
    const float* bt    = (const float*)d_in[7];

    char* ws = (char*)d_ws;
    unsigned int* xT   = (unsigned int*)ws;                  // 33,554,432 B
    float2* meanmaxP   = (float2*)(ws + 33554432);           // 1,048,576 B
    unsigned int* ybuf = (unsigned int*)(ws + 34603008);     // 41,943,040 B
    unsigned int* rec  = (unsigned int*)(ws + 76546048);     // 7,864,320 B
    float* gsum        = (float*)(ws + 84410368);            // 512 B
    float* gsq         = gsum + NCH;                         // 512 B

    transpose_x_kernel<<<HW / 128, 256, 0, stream>>>(x_f4, xT, meanmaxP);
    mult_kernel<<<L_TOTAL / 256, 256, 0, stream>>>(meanmaxP, cks, aw, ab, rec, gsum);
    gather_kernel<<<(L_TOTAL / LPB) * NGRP, 256, 0, stream>>>(
        xT, rec, dw, db, ybuf, gsum, gsq);
    finalize_kernel<<<1280, 256, 0, stream>>>(
        (const u32x4*)ybuf, gsum, gsq, gm, bt, (float*)d_out);
}